// Round 6
// baseline (104.192 us; speedup 1.0000x reference)
//
#include <hip/hip_runtime.h>
#include <stdint.h>

typedef __attribute__((ext_vector_type(8))) short short8;
typedef __attribute__((ext_vector_type(4))) short short4v;
typedef __attribute__((ext_vector_type(4))) float f32x4;
typedef __attribute__((ext_vector_type(2))) unsigned int uint2v;

#define S_LEN 4096
#define NBATCH 2
#define DMODEL 768
#define NH 12
#define HD 64
#define MROWS (S_LEN * NBATCH)   // 8192

__device__ __forceinline__ unsigned short f2bf(float f) {
    unsigned int u = __builtin_bit_cast(unsigned int, f);
    u += 0x7fffu + ((u >> 16) & 1u);       // round-to-nearest-even
    return (unsigned short)(u >> 16);
}

// async global->LDS, 16B per lane; LDS dst = wave-uniform base + lane*16,
// global src is PER-LANE (carries the within-row chunk swizzle).
#define GLDS16(gp, lp) __builtin_amdgcn_global_load_lds( \
    (const __attribute__((address_space(1))) void*)(gp), \
    (__attribute__((address_space(3))) void*)(lp), 16, 0, 0)

#define MFMA_BF16 __builtin_amdgcn_mfma_f32_16x16x32_bf16

// ---------------- kernel 1: val fp32 -> X bf16 (8192 x 768) ----------------
__global__ __launch_bounds__(256) void cvt_val_kernel(const float* __restrict__ in,
                                                      short* __restrict__ out) {
    size_t i = (size_t)blockIdx.x * 256 + threadIdx.x;
    const f32x4 v = *(const f32x4*)(in + i * 4);
    short4v o;
    o.x = (short)f2bf(v.x); o.y = (short)f2bf(v.y);
    o.z = (short)f2bf(v.z); o.w = (short)f2bf(v.w);
    *(short4v*)(out + i * 4) = o;
}

// --- kernel 2: W fp32 (K x N) -> WT bf16 (z-major, [n][k]) ---
__global__ __launch_bounds__(256) void cvt_w_kernel(const float* __restrict__ Wq,
                                                    const float* __restrict__ Wk,
                                                    const float* __restrict__ Wv,
                                                    short* __restrict__ WT) {
    const int z = blockIdx.z;
    const float* W = (z == 0) ? Wq : ((z == 1) ? Wk : Wv);
    const int n  = blockIdx.x * 256 + threadIdx.x;
    const int k0 = blockIdx.y * 8;
    short8 o;
#pragma unroll
    for (int i = 0; i < 8; ++i)
        o[i] = (short)f2bf(W[(size_t)(k0 + i) * DMODEL + n]);
    *(short8*)(WT + (size_t)z * DMODEL * DMODEL + (size_t)n * DMODEL + k0) = o;
}

// ------- kernel 3: fused QKV GEMM, 256x256 tile, BK=64, 8-wave 4-phase -------
// 2-slot LDS dbuf (128 KB). Per K-tile: 4 phases x 16 MFMA. Halves of tile
// t+2 staged at P2 (B) / P3 (A) into the slot freed phase-by-phase by tile t.
// Counted vmcnt(8) once per K-tile; LDS chunk-XOR swizzle both-sides (rule 21).
#define KTILES 12
__global__ __launch_bounds__(512, 2) void gemm_qkv_kernel(
    const short* __restrict__ X, const short* __restrict__ WT,
    const float* __restrict__ bq, const float* __restrict__ bk, const float* __restrict__ bv,
    short* __restrict__ Q, short* __restrict__ K, short* __restrict__ V)
{
    __shared__ __align__(16) short SMEM[65536];   // 128 KB; reused as C[128][264] in epilogue
    short* As = SMEM;            // [2][256*64]
    short* Bs = SMEM + 32768;    // [2][256*64]

    const int phys = blockIdx.x;                 // 288 = 8 XCD * (9 n * 4 m), m-fastest
    const int xcd = phys & 7, ii = phys >> 3;
    const int m0  = (xcd * 4 + (ii & 3)) * 256;
    const int nf  = (ii >> 2) * 256;
    const int z   = nf / DMODEL;
    const int n0w = nf - z * DMODEL;

    const int tid = threadIdx.x, lane = tid & 63, wid = tid >> 6;
    const int wm = wid >> 2, wn = wid & 3;       // 2M x 4N waves
    const int fr = lane & 15, kg = lane >> 4;

    const float* bias = (z == 0) ? bq : ((z == 1) ? bk : bv);
    short*       OUT  = (z == 0) ? Q  : ((z == 1) ? K  : V);

    f32x4 acc[8][4];
#pragma unroll
    for (int i = 0; i < 8; ++i)
#pragma unroll
        for (int j = 0; j < 4; ++j) acc[i][j] = (f32x4){0.f, 0.f, 0.f, 0.f};

    // staging: thread covers LDS pos tid (+512); row = pos>>3, LDS slot = pos&7;
    // global source chunk pre-swizzled: gchunk = (pos&7) ^ (row&7)  (rule 21)
    const int srow   = tid >> 3;                 // 0..63
    const int schunk = (tid & 7) ^ (srow & 7);
    const short* srcA = X + (size_t)(m0 + srow) * DMODEL + schunk * 8;
    const short* srcB = WT + (size_t)z * DMODEL * DMODEL
                           + (size_t)(n0w + srow) * DMODEL + schunk * 8;

#define STAGE_A(sl, h, kt) do { \
    GLDS16(srcA + (size_t)((h) * 128)      * DMODEL + (kt), As + (sl) + (h) * 8192 + tid * 8);        \
    GLDS16(srcA + (size_t)((h) * 128 + 64) * DMODEL + (kt), As + (sl) + (h) * 8192 + 4096 + tid * 8); \
  } while (0)
#define STAGE_B(sl, h, kt) do { \
    GLDS16(srcB + (size_t)((h) * 128)      * DMODEL + (kt), Bs + (sl) + (h) * 8192 + tid * 8);        \
    GLDS16(srcB + (size_t)((h) * 128 + 64) * DMODEL + (kt), Bs + (sl) + (h) * 8192 + 4096 + tid * 8); \
  } while (0)

    // fragment read offsets (shorts); read slot = chunk ^ (row&7), row&7 == fr&7
    const int arow0 = (wm * 128 + fr) * 64;
    const int brow0 = (wn * 64 + fr) * 64;
    const int swz0  = (kg ^ (fr & 7)) * 8;         // k-half 0 (chunk kg)
    const int swz1  = ((4 + kg) ^ (fr & 7)) * 8;   // k-half 1 (chunk 4+kg)

    // prologue: tiles 0,1 fully staged; gate leaves tile 1 (8 loads) in flight
    STAGE_B(0, 0, 0);  STAGE_B(0, 1, 0);  STAGE_A(0, 0, 0);  STAGE_A(0, 1, 0);
    STAGE_B(16384, 0, 64); STAGE_B(16384, 1, 64); STAGE_A(16384, 0, 64); STAGE_A(16384, 1, 64);
    asm volatile("s_waitcnt vmcnt(8)" ::: "memory");
    __builtin_amdgcn_sched_barrier(0);
    __builtin_amdgcn_s_barrier();

    short8 af[4][2], bl[2][2], bh2[2][2];

    for (int t = 0; t < KTILES; ++t) {
        const int sl = (t & 1) * 16384;           // current slot; t+2 stages land here too
        const short* Ab = As + sl;
        const short* Bb = Bs + sl;
        const int kt2 = (t + 2) * 64;

        // ---- P0: read A-quarter lo (mi 0..3) + B lo (ni 0..1); MFMA (lo,lo) ----
#pragma unroll
        for (int mi = 0; mi < 4; ++mi) {
            af[mi][0] = *(const short8*)(Ab + arow0 + mi * 1024 + swz0);
            af[mi][1] = *(const short8*)(Ab + arow0 + mi * 1024 + swz1);
        }
#pragma unroll
        for (int ni = 0; ni < 2; ++ni) {
            bl[ni][0] = *(const short8*)(Bb + brow0 + ni * 1024 + swz0);
            bl[ni][1] = *(const short8*)(Bb + brow0 + ni * 1024 + swz1);
        }
        __builtin_amdgcn_s_barrier();
        asm volatile("s_waitcnt lgkmcnt(0)" ::: "memory");
        __builtin_amdgcn_sched_barrier(0);
        __builtin_amdgcn_s_setprio(1);
#pragma unroll
        for (int mi = 0; mi < 4; ++mi)
#pragma unroll
            for (int ni = 0; ni < 2; ++ni) {
                acc[mi][ni] = MFMA_BF16(af[mi][0], bl[ni][0], acc[mi][ni], 0, 0, 0);
                acc[mi][ni] = MFMA_BF16(af[mi][1], bl[ni][1], acc[mi][ni], 0, 0, 0);
            }
        __builtin_amdgcn_s_setprio(0);
        __builtin_amdgcn_s_barrier();

        // ---- P1: read B hi (ni 2..3); MFMA (lo,hi) ----
#pragma unroll
        for (int nj = 0; nj < 2; ++nj) {
            bh2[nj][0] = *(const short8*)(Bb + brow0 + (2 + nj) * 1024 + swz0);
            bh2[nj][1] = *(const short8*)(Bb + brow0 + (2 + nj) * 1024 + swz1);
        }
        __builtin_amdgcn_s_barrier();
        asm volatile("s_waitcnt lgkmcnt(0)" ::: "memory");
        __builtin_amdgcn_sched_barrier(0);
        __builtin_amdgcn_s_setprio(1);
#pragma unroll
        for (int mi = 0; mi < 4; ++mi)
#pragma unroll
            for (int nj = 0; nj < 2; ++nj) {
                acc[mi][2 + nj] = MFMA_BF16(af[mi][0], bh2[nj][0], acc[mi][2 + nj], 0, 0, 0);
                acc[mi][2 + nj] = MFMA_BF16(af[mi][1], bh2[nj][1], acc[mi][2 + nj], 0, 0, 0);
            }
        __builtin_amdgcn_s_setprio(0);
        __builtin_amdgcn_s_barrier();

        // ---- P2: read A-quarter hi (mi 4..7); stage B(t+2) [freed at P1]; MFMA (hi,hi) ----
#pragma unroll
        for (int mi = 0; mi < 4; ++mi) {
            af[mi][0] = *(const short8*)(Ab + arow0 + (4 + mi) * 1024 + swz0);
            af[mi][1] = *(const short8*)(Ab + arow0 + (4 + mi) * 1024 + swz1);
        }
        if (t < KTILES - 2) { STAGE_B(sl, 0, kt2); STAGE_B(sl, 1, kt2); }
        __builtin_amdgcn_s_barrier();
        asm volatile("s_waitcnt lgkmcnt(0)" ::: "memory");
        __builtin_amdgcn_sched_barrier(0);
        __builtin_amdgcn_s_setprio(1);
#pragma unroll
        for (int mi = 0; mi < 4; ++mi)
#pragma unroll
            for (int nj = 0; nj < 2; ++nj) {
                acc[4 + mi][2 + nj] = MFMA_BF16(af[mi][0], bh2[nj][0], acc[4 + mi][2 + nj], 0, 0, 0);
                acc[4 + mi][2 + nj] = MFMA_BF16(af[mi][1], bh2[nj][1], acc[4 + mi][2 + nj], 0, 0, 0);
            }
        __builtin_amdgcn_s_setprio(0);
        __builtin_amdgcn_s_barrier();

        // ---- P3: stage A(t+2) [freed at P2]; MFMA (hi,lo) reg-only; vmcnt gate; 1 barrier ----
        if (t < KTILES - 2) { STAGE_A(sl, 0, kt2); STAGE_A(sl, 1, kt2); }
        __builtin_amdgcn_s_setprio(1);
#pragma unroll
        for (int mi = 0; mi < 4; ++mi)
#pragma unroll
            for (int ni = 0; ni < 2; ++ni) {
                acc[4 + mi][ni] = MFMA_BF16(af[mi][0], bl[ni][0], acc[4 + mi][ni], 0, 0, 0);
                acc[4 + mi][ni] = MFMA_BF16(af[mi][1], bl[ni][1], acc[4 + mi][ni], 0, 0, 0);
            }
        __builtin_amdgcn_s_setprio(0);
        if (t < KTILES - 2)      { asm volatile("s_waitcnt vmcnt(8)" ::: "memory"); }
        else if (t == KTILES - 2){ asm volatile("s_waitcnt vmcnt(0)" ::: "memory"); }
        __builtin_amdgcn_sched_barrier(0);
        __builtin_amdgcn_s_barrier();
    }
#undef STAGE_A
#undef STAGE_B

    // ---- epilogue: 2 chunks of 128 rows through LDS, coalesced bf16 stores ----
    const float scale = (z == 0) ? 0.125f : 1.0f;   // q /= sqrt(64)
    float bval[4];
#pragma unroll
    for (int ni = 0; ni < 4; ++ni) bval[ni] = bias[n0w + wn * 64 + ni * 16 + fr];

    short* Cs = SMEM;                               // [128][264]
    for (int mh = 0; mh < 2; ++mh) {
        if (wm == mh) {
#pragma unroll
            for (int mi = 0; mi < 8; ++mi)
#pragma unroll
                for (int ni = 0; ni < 4; ++ni)
#pragma unroll
                    for (int r = 0; r < 4; ++r)
                        Cs[(mi * 16 + 4 * kg + r) * 264 + wn * 64 + ni * 16 + fr] =
                            (short)f2bf((acc[mi][ni][r] + bval[ni]) * scale);
        }
        __syncthreads();
#pragma unroll
        for (int it = 0; it < 8; ++it) {            // 4096 chunks of 8 elems
            const int flat = it * 512 + tid;
            const int row = flat >> 5, c8 = (flat & 31) * 8;
            const int gm = m0 + mh * 128 + row, gn = n0w + c8;
            const int s = gm >> 1, bb = gm & 1, hh = gn >> 6, e0 = gn & 63;
            *(short8*)(&OUT[((size_t)(bb * NH + hh) * S_LEN + s) * HD + e0]) =
                *(const short8*)(&Cs[row * 264 + c8]);
        }
        __syncthreads();
    }
}

// ---------------- kernel 4: V [bh][s][e] -> Vt [bh][e][s] ----------------
__global__ __launch_bounds__(256) void transpose_v_kernel(const short* __restrict__ V,
                                                          short* __restrict__ Vt) {
    __shared__ __align__(16) short T[64][72];
    const int bh = blockIdx.x;
    const int s0 = blockIdx.y * 64;
    const int t  = threadIdx.x;
    const short* Vb  = V  + (size_t)bh * S_LEN * HD;
    short*       Vtb = Vt + (size_t)bh * HD * S_LEN;

    const int sl = t >> 3, e0 = (t & 7) * 8;
#pragma unroll
    for (int i = 0; i < 2; ++i) {
        short8 v = *(const short8*)(Vb + (size_t)(s0 + sl + i * 32) * HD + e0);
        *(short8*)(&T[sl + i * 32][e0]) = v;
    }
    __syncthreads();
    const int e  = t & 63;
    const int sb = (t >> 6) * 16;
    short vv[16];
#pragma unroll
    for (int j = 0; j < 16; ++j) vv[j] = T[sb + j][e];
    short8 a, b;
#pragma unroll
    for (int j = 0; j < 8; ++j) { a[j] = vv[j]; b[j] = vv[8 + j]; }
    *(short8*)(Vtb + (size_t)e * S_LEN + s0 + sb)     = a;
    *(short8*)(Vtb + (size_t)e * S_LEN + s0 + sb + 8) = b;
}

// ---------------- kernel 5: banded causal attention, 8 waves x 16 queries ----------------
#define QB   128
#define KWIN 384
#define KST  72     // K LDS row stride (elems): 144B -> 4-bank rotation per row
#define VST  392    // Vt LDS row stride: 784B -> 4-bank rotation per row
#define PCST 40     // P chunk buffer row stride (80B, 16B-aligned rows)

__global__ __launch_bounds__(512, 2) void attn_kernel(
    const short* __restrict__ Q, const short* __restrict__ K,
    const short* __restrict__ Vt, float* __restrict__ out)
{
    __shared__ __align__(16) short Ks[KWIN * KST];        // 55296 B
    __shared__ __align__(16) short Vs[HD * VST];          // 50176 B
    __shared__ __align__(16) short Pc[8][2][16 * PCST];   // 20480 B  (per-wave ping-pong)

    const int tid = threadIdx.x, lane = tid & 63, wid = tid >> 6;
    const int q0 = blockIdx.x * QB;
    const int bh = blockIdx.y;
    const int bb = bh / NH, hh = bh % NH;
    const int fr = lane & 15, g = lane >> 4;
    const int kstart = q0 - 256;

    const short* Qb = Q  + (size_t)bh * S_LEN * HD;
    const short* Kb = K  + (size_t)bh * S_LEN * HD;
    const short* Vb = Vt + (size_t)bh * HD * S_LEN;

    // ---- cooperative staging (coalesced 16B segments) ----
#pragma unroll
    for (int it = 0; it < 6; ++it) {                 // K: 384 rows x 64 elems
        const int seg = it * 512 + tid;
        const int row = seg >> 3, c8 = (seg & 7) * 8;
        int sr = kstart + row; sr = sr < 0 ? 0 : sr;  // garbage rows masked later
        *(short8*)(Ks + row * KST + c8) = *(const short8*)(Kb + (size_t)sr * HD + c8);
    }
#pragma unroll
    for (int it = 0; it < 6; ++it) {                 // Vt: 64 rows x 384 key-cols
        const int seg = it * 512 + tid;
        const int row = seg / 48, cc = seg % 48;
        int sk = kstart + cc * 8; sk = sk < 0 ? 0 : sk;
        *(short8*)(Vs + row * VST + cc * 8) = *(const short8*)(Vb + (size_t)row * S_LEN + sk);
    }
    __syncthreads();

    // ---- Q fragments (B-operand: col=query=fr, k=8g+i) ----
    const int qrow = q0 + wid * 16 + fr;
    const short8 qa0 = *(const short8*)(Qb + (size_t)qrow * HD + g * 8);
    const short8 qa1 = *(const short8*)(Qb + (size_t)qrow * HD + 32 + g * 8);

    // ---- QK^T: 17 tiles ----
    float sc[17][4];
#pragma unroll
    for (int t = 0; t < 17; ++t) {
        const short* kr = Ks + ((wid + t) * 16 + fr) * KST;   // A row = key
        const short8 a0 = *(const short8*)(kr + g * 8);
        const short8 a1 = *(const short8*)(kr + 32 + g * 8);
        f32x4 d = {0.f, 0.f, 0.f, 0.f};
        d = MFMA_BF16(a0, qa0, d, 0, 0, 0);
        d = MFMA_BF16(a1, qa1, d, 0, 0, 0);
        const int gk0 = kstart + (wid + t) * 16 + 4 * g;      // global key (+r)
#pragma unroll
        for (int r = 0; r < 4; ++r) {
            const int dd = 256 + fr - 16 * t - 4 * g - r;     // query - key
            const bool ok = (dd >= 0) & (dd <= 256) & (gk0 + r >= 0);
            sc[t][r] = ok ? d[r] : -1e30f;
        }
    }

    // ---- softmax max (row = query = fr; reduce across g-groups) ----
    float mx = -1e30f;
#pragma unroll
    for (int t = 0; t < 17; ++t)
#pragma unroll
        for (int r = 0; r < 4; ++r) mx = fmaxf(mx, sc[t][r]);
    mx = fmaxf(mx, __shfl_xor(mx, 16));
    mx = fmaxf(mx, __shfl_xor(mx, 32));

    // ---- chunked exp + P redistribute (per-wave LDS, no barrier) + PV ----
    float sm = 0.f;
    f32x4 o[4];
#pragma unroll
    for (int et = 0; et < 4; ++et) o[et] = (f32x4){0.f, 0.f, 0.f, 0.f};

#pragma unroll
    for (int c = 0; c < 9; ++c) {
        float pv[8];
#pragma unroll
        for (int j = 0; j < 8; ++j) {
            const int t = 2 * c + (j >> 2);
            pv[j] = (t < 17) ? __expf(sc[t][j & 3] - mx) : 0.f;   // masked -> exp(-1e30)=0
            sm += pv[j];
        }
        unsigned int u0 = (unsigned)f2bf(pv[0]) | ((unsigned)f2bf(pv[1]) << 16);
        unsigned int u1 = (unsigned)f2bf(pv[2]) | ((unsigned)f2bf(pv[3]) << 16);
        unsigned int u2 = (unsigned)f2bf(pv[4]) | ((unsigned)f2bf(pv[5]) << 16);
        unsigned int u3 = (unsigned)f2bf(pv[6]) | ((unsigned)f2bf(pv[7]) << 16);
        short* pb = &Pc[wid][c & 1][0];
        *(uint2v*)(pb + fr * PCST + 4 * g)      = (uint2v){u0, u1};  // keys 4g..4g+3 (tile 2c)
        *(uint2v*)(pb + fr * PCST + 16 + 4 * g) = (uint2v){u2, u3};  // keys 16+4g..  (tile 2c+1)
        const short8 pa = *(const short8*)(pb + fr * PCST + 8 * g);  // A-frag: q=fr, k=8g..
        int ka = wid * 16 + 32 * c + 8 * g;
        ka = ka > KWIN - 8 ? KWIN - 8 : ka;        // clamped lanes have P=0
#pragma unroll
        for (int et = 0; et < 4; ++et) {
            const short8 vb = *(const short8*)(Vs + (et * 16 + fr) * VST + ka);
            o[et] = MFMA_BF16(pa, vb, o[et], 0, 0, 0);
        }
    }

    sm += __shfl_xor(sm, 16);
    sm += __shfl_xor(sm, 32);
    const float inv = 1.0f / sm;                   // valid for query = fr
    float inv4[4];
#pragma unroll
    for (int r = 0; r < 4; ++r) inv4[r] = __shfl(inv, 4 * g + r);   // PV D-row = query 4g+r

#pragma unroll
    for (int et = 0; et < 4; ++et)
#pragma unroll
        for (int r = 0; r < 4; ++r) {
            const int qi = q0 + wid * 16 + 4 * g + r;
            const int dd = hh * HD + et * 16 + fr;
            out[((size_t)qi * NBATCH + bb) * DMODEL + dd] = o[et][r] * inv4[r];
        }
}

extern "C" void kernel_launch(void* const* d_in, const int* in_sizes, int n_in,
                              void* d_out, int out_size, void* d_ws, size_t ws_size,
                              hipStream_t stream) {
    (void)in_sizes; (void)n_in; (void)out_size; (void)ws_size;
    const float* val = (const float*)d_in[0];
    const float* Wq  = (const float*)d_in[1];
    const float* bq  = (const float*)d_in[2];
    const float* Wk  = (const float*)d_in[3];
    const float* bk  = (const float*)d_in[4];
    const float* Wv  = (const float*)d_in[5];
    const float* bv  = (const float*)d_in[6];
    float* out = (float*)d_out;

    char* ws = (char*)d_ws;
    const size_t SZ_X  = (size_t)MROWS * DMODEL * 2;
    const size_t SZ_W  = (size_t)DMODEL * DMODEL * 2;
    short* X  = (short*)(ws);
    short* WT = (short*)(ws + SZ_X);
    short* Qb = (short*)(ws + SZ_X + 3 * SZ_W);
    short* Kb = (short*)(ws + SZ_X + 3 * SZ_W + SZ_X);
    short* Vb = (short*)(ws + SZ_X + 3 * SZ_W + 2 * SZ_X);
    short* Vt = (short*)(ws + SZ_X + 3 * SZ_W + 3 * SZ_X);

    cvt_val_kernel<<<dim3((MROWS * DMODEL) / 4 / 256), dim3(256), 0, stream>>>(val, X);
    cvt_w_kernel<<<dim3(3, 96, 3), dim3(256), 0, stream>>>(Wq, Wk, Wv, WT);
    gemm_qkv_kernel<<<dim3(288), dim3(512), 0, stream>>>(
        X, WT, bq, bk, bv, Qb, Kb, Vb);
    transpose_v_kernel<<<dim3(NBATCH * NH, S_LEN / 64), dim3(256), 0, stream>>>(Vb, Vt);
    attn_kernel<<<dim3(S_LEN / QB, NBATCH * NH), dim3(512), 0, stream>>>(Qb, Kb, Vt, out);
}

// Round 7
// 93.917 us; speedup vs baseline: 1.1094x; 1.1094x over previous
//
#include <hip/hip_runtime.h>
#include <stdint.h>

typedef __attribute__((ext_vector_type(8))) short short8;
typedef __attribute__((ext_vector_type(4))) short short4v;
typedef __attribute__((ext_vector_type(4))) float f32x4;
typedef __attribute__((ext_vector_type(2))) unsigned int uint2v;

#define S_LEN 4096
#define NBATCH 2
#define DMODEL 768
#define NH 12
#define HD 64
#define MROWS (S_LEN * NBATCH)   // 8192

__device__ __forceinline__ unsigned short f2bf(float f) {
    unsigned int u = __builtin_bit_cast(unsigned int, f);
    u += 0x7fffu + ((u >> 16) & 1u);       // round-to-nearest-even
    return (unsigned short)(u >> 16);
}

// async global->LDS, 16B per lane; LDS dst = wave-uniform base + lane*16,
// global src is PER-LANE (carries the within-row slot swizzle).
#define GLDS16(gp, lp) __builtin_amdgcn_global_load_lds( \
    (const __attribute__((address_space(1))) void*)(gp), \
    (__attribute__((address_space(3))) void*)(lp), 16, 0, 0)

#define MFMA_BF16 __builtin_amdgcn_mfma_f32_16x16x32_bf16

// ---------------- kernel 1: val fp32 -> X bf16 (8192 x 768) ----------------
__global__ __launch_bounds__(256) void cvt_val_kernel(const float* __restrict__ in,
                                                      short* __restrict__ out) {
    size_t i = (size_t)blockIdx.x * 256 + threadIdx.x;
    const f32x4 v = *(const f32x4*)(in + i * 4);
    short4v o;
    o.x = (short)f2bf(v.x); o.y = (short)f2bf(v.y);
    o.z = (short)f2bf(v.z); o.w = (short)f2bf(v.w);
    *(short4v*)(out + i * 4) = o;
}

// --- kernel 2: W fp32 (K x N) -> WT bf16 (z-major, [n][k]) ---
__global__ __launch_bounds__(256) void cvt_w_kernel(const float* __restrict__ Wq,
                                                    const float* __restrict__ Wk,
                                                    const float* __restrict__ Wv,
                                                    short* __restrict__ WT) {
    const int z = blockIdx.z;
    const float* W = (z == 0) ? Wq : ((z == 1) ? Wk : Wv);
    const int n  = blockIdx.x * 256 + threadIdx.x;
    const int k0 = blockIdx.y * 8;
    short8 o;
#pragma unroll
    for (int i = 0; i < 8; ++i)
        o[i] = (short)f2bf(W[(size_t)(k0 + i) * DMODEL + n]);
    *(short8*)(WT + (size_t)z * DMODEL * DMODEL + (size_t)n * DMODEL + k0) = o;
}

// ------- kernel 3: fused QKV GEMM, 128x256 tile, BK=32, 8 waves -------
// R5's proven 3-buffer counted-vmcnt glds pipeline; B staged once per 2x M
// (27% less staging traffic); 2 blocks/CU (72 KB LDS) = 16 waves/CU.
// z==2 writes V directly TRANSPOSED ([bh][e][s]) from the LDS C-tile.
#define NT 24   // 768/32 K-steps
__global__ __launch_bounds__(512, 4) void gemm_qkv_kernel(
    const short* __restrict__ X, const short* __restrict__ WT,
    const float* __restrict__ bq, const float* __restrict__ bk, const float* __restrict__ bv,
    short* __restrict__ Q, short* __restrict__ K, short* __restrict__ Vt)
{
    __shared__ __align__(16) short SMEM[36864];   // 72 KB: A[3][4096] | B[3][8192]; C[128][264] reuse
    short* As = SMEM;            // 3 * 4096 shorts
    short* Bs = SMEM + 12288;    // 3 * 8192 shorts

    const int phys = blockIdx.x;                 // 576 = 8 XCD * (8 m * 9 n), n-fastest in XCD
    const int xcd = phys & 7, ii = phys >> 3;
    const int m0  = (xcd * 8 + ii / 9) * 128;
    const int nf  = (ii % 9) * 256;
    const int z   = nf / DMODEL;                 // tiles 0-2:q 3-5:k 6-8:v (exact boundaries)
    const int n0w = nf - z * DMODEL;

    const int tid = threadIdx.x, lane = tid & 63, wid = tid >> 6;
    const int wm = wid >> 2, wn = wid & 3;       // 2M x 4N waves, wave-tile 64x64
    const int fr = lane & 15, kg = lane >> 4;
    const int wr = wm * 64, wc = wn * 64;

    const float* bias = (z == 0) ? bq : ((z == 1) ? bk : bv);
    short*       OUT  = (z == 0) ? Q  : ((z == 1) ? K  : Vt);

    f32x4 acc[4][4];
#pragma unroll
    for (int i = 0; i < 4; ++i)
#pragma unroll
        for (int j = 0; j < 4; ++j) acc[i][j] = (f32x4){0.f, 0.f, 0.f, 0.f};

    // staging: pos = j*512+tid -> row = pos>>2, slot = pos&3 (16B within 64B row).
    // global slot pre-swizzled: gslot = (lane&3) ^ ((row>>1)&3); (row>>1)&3 ==
    // (lane>>3)&3 for every j (higher row bits are multiples of 4). Rule 21.
    const int gslot = (lane & 3) ^ ((lane >> 3) & 3);
    const int grow  = wid * 16 + (lane >> 2);
    const short* srcA = X  + (size_t)(m0 + grow) * DMODEL + gslot * 8;
    const short* srcB = WT + (size_t)z * DMODEL * DMODEL
                           + (size_t)(n0w + grow) * DMODEL + gslot * 8;

#define STAGE(buf, kt) do { \
        GLDS16(srcA + (kt),                As + (buf) * 4096 + wid * 512);        \
        GLDS16(srcB + (kt),                Bs + (buf) * 8192 + wid * 512);        \
        GLDS16(srcB + (kt) + 128 * DMODEL, Bs + (buf) * 8192 + 4096 + wid * 512); \
    } while (0)

    STAGE(0, 0);
    STAGE(1, 32);
    const int rslot = (fr >> 1) & 3;             // read-side swizzle (same involution)
    for (int t = 0; t < NT; ++t) {
        // per-wave wait for OWN tile-t loads (3/stage); keep t+1,t+2 in flight
        if (t + 2 < NT) { asm volatile("s_waitcnt vmcnt(3)" ::: "memory"); }
        else            { asm volatile("s_waitcnt vmcnt(0)" ::: "memory"); }
        __builtin_amdgcn_sched_barrier(0);
        __builtin_amdgcn_s_barrier();            // tile t fully in LDS for all waves
        __builtin_amdgcn_sched_barrier(0);
        if (t + 2 < NT) STAGE((t + 2) % 3, (t + 2) * 32);   // WAR-safe post-barrier

        const short* Ab = As + (t % 3) * 4096;
        const short* Bb = Bs + (t % 3) * 8192;
        short8 af[4], bfv[4];
#pragma unroll
        for (int mi = 0; mi < 4; ++mi)
            af[mi] = *(const short8*)(Ab + (wr + mi * 16 + fr) * 32 + (kg ^ rslot) * 8);
#pragma unroll
        for (int ni = 0; ni < 4; ++ni)
            bfv[ni] = *(const short8*)(Bb + (wc + ni * 16 + fr) * 32 + (kg ^ rslot) * 8);
        __builtin_amdgcn_s_setprio(1);
#pragma unroll
        for (int mi = 0; mi < 4; ++mi)
#pragma unroll
            for (int ni = 0; ni < 4; ++ni)
                acc[mi][ni] = MFMA_BF16(af[mi], bfv[ni], acc[mi][ni], 0, 0, 0);
        __builtin_amdgcn_s_setprio(0);
    }
#undef STAGE

    __syncthreads();                        // staging LDS dead; repurpose for C tile
    // q scale folds 1/sqrt(64) AND log2(e) (attn uses exp2)
    const float scale = (z == 0) ? 0.18033688f : 1.0f;
    float bval[4];
#pragma unroll
    for (int ni = 0; ni < 4; ++ni) bval[ni] = bias[n0w + wc + ni * 16 + fr];

    short* Cs = SMEM;                       // [128][264] bf16 (33792 shorts <= 36864)
#pragma unroll
    for (int mi = 0; mi < 4; ++mi)
#pragma unroll
        for (int ni = 0; ni < 4; ++ni)
#pragma unroll
            for (int r = 0; r < 4; ++r)
                Cs[(wr + mi * 16 + 4 * kg + r) * 264 + (wc + ni * 16 + fr)] =
                    (short)f2bf((acc[mi][ni][r] + bval[ni]) * scale);
    __syncthreads();

    if (z < 2) {                            // Q/K: [bh][s][e], coalesced short8
#pragma unroll
        for (int it = 0; it < 8; ++it) {    // 4096 chunks of 8 elems
            const int flat = it * 512 + tid;
            const int row = flat >> 5, c8 = (flat & 31) * 8;
            const int gm = m0 + row, gn = n0w + c8;
            const int s = gm >> 1, bb = gm & 1, hh = gn >> 6, e0 = gn & 63;
            *(short8*)(&OUT[((size_t)(bb * NH + hh) * S_LEN + s) * HD + e0]) =
                *(const short8*)(&Cs[row * 264 + c8]);
        }
    } else {                                // V: write transposed [bh][e][s]
#pragma unroll
        for (int it = 0; it < 8; ++it) {
            const int flat = it * 512 + tid;
            const int sc = flat & 7;                 // 8-s chunk
            const int e  = (flat >> 3) & 63;
            const int q  = flat >> 9;                // b + 2*hl
            const int b  = q & 1, hl = q >> 1;
            short8 v;
#pragma unroll
            for (int j = 0; j < 8; ++j)
                v[j] = Cs[((sc * 8 + j) * 2 + b) * 264 + hl * 64 + e];
            const int bh = b * NH + (n0w >> 6) + hl;
            *(short8*)(&OUT[(size_t)bh * HD * S_LEN + (size_t)e * S_LEN
                            + (m0 >> 1) + sc * 8]) = v;
        }
    }
}

// ---------------- kernel 4: banded causal attention, 8 waves x 16 queries ----------------
#define QB   128
#define KWIN 384
#define KST  72     // K LDS row stride (elems): 144B -> 4-bank rotation per row
#define VST  392    // Vt LDS row stride: 784B -> 4-bank rotation per row
#define PCST 40     // P chunk buffer row stride (80B, 16B-aligned rows)

__global__ __launch_bounds__(512, 2) void attn_kernel(
    const short* __restrict__ Q, const short* __restrict__ K,
    const short* __restrict__ Vt, float* __restrict__ out)
{
    __shared__ __align__(16) short Ks[KWIN * KST];        // 55296 B
    __shared__ __align__(16) short Vs[HD * VST];          // 50176 B
    __shared__ __align__(16) short Pc[8][2][16 * PCST];   // 20480 B  (per-wave ping-pong)

    const int tid = threadIdx.x, lane = tid & 63, wid = tid >> 6;
    const int q0 = blockIdx.x * QB;
    const int bh = blockIdx.y;
    const int bb = bh / NH, hh = bh % NH;
    const int fr = lane & 15, g = lane >> 4;
    const int kstart = q0 - 256;

    const short* Qb = Q  + (size_t)bh * S_LEN * HD;
    const short* Kb = K  + (size_t)bh * S_LEN * HD;
    const short* Vb = Vt + (size_t)bh * HD * S_LEN;

    // ---- cooperative staging (coalesced 16B segments) ----
#pragma unroll
    for (int it = 0; it < 6; ++it) {                 // K: 384 rows x 64 elems
        const int seg = it * 512 + tid;
        const int row = seg >> 3, c8 = (seg & 7) * 8;
        int sr = kstart + row; sr = sr < 0 ? 0 : sr;  // garbage rows masked later
        *(short8*)(Ks + row * KST + c8) = *(const short8*)(Kb + (size_t)sr * HD + c8);
    }
#pragma unroll
    for (int it = 0; it < 6; ++it) {                 // Vt: 64 rows x 384 key-cols
        const int seg = it * 512 + tid;
        const int row = seg / 48, cc = seg % 48;
        int sk = kstart + cc * 8; sk = sk < 0 ? 0 : sk;
        *(short8*)(Vs + row * VST + cc * 8) = *(const short8*)(Vb + (size_t)row * S_LEN + sk);
    }
    __syncthreads();

    // ---- Q fragments (B-operand: col=query=fr, k=8g+i) ----
    const int qrow = q0 + wid * 16 + fr;
    const short8 qa0 = *(const short8*)(Qb + (size_t)qrow * HD + g * 8);
    const short8 qa1 = *(const short8*)(Qb + (size_t)qrow * HD + 32 + g * 8);

    // ---- QK^T: 17 tiles ----
    float sc[17][4];
#pragma unroll
    for (int t = 0; t < 17; ++t) {
        const short* kr = Ks + ((wid + t) * 16 + fr) * KST;   // A row = key
        const short8 a0 = *(const short8*)(kr + g * 8);
        const short8 a1 = *(const short8*)(kr + 32 + g * 8);
        f32x4 d = {0.f, 0.f, 0.f, 0.f};
        __builtin_amdgcn_s_setprio(1);
        d = MFMA_BF16(a0, qa0, d, 0, 0, 0);
        d = MFMA_BF16(a1, qa1, d, 0, 0, 0);
        __builtin_amdgcn_s_setprio(0);
        const int gk0 = kstart + (wid + t) * 16 + 4 * g;      // global key (+r)
#pragma unroll
        for (int r = 0; r < 4; ++r) {
            const int dd = 256 + fr - 16 * t - 4 * g - r;     // query - key
            const bool ok = (dd >= 0) & (dd <= 256) & (gk0 + r >= 0);
            sc[t][r] = ok ? d[r] : -1e30f;
        }
    }

    // ---- softmax max (row = query = fr; reduce across g-groups) ----
    float mx = -1e30f;
#pragma unroll
    for (int t = 0; t < 17; ++t)
#pragma unroll
        for (int r = 0; r < 4; ++r) mx = fmaxf(mx, sc[t][r]);
    mx = fmaxf(mx, __shfl_xor(mx, 16));
    mx = fmaxf(mx, __shfl_xor(mx, 32));

    // ---- chunked exp2 + P redistribute (per-wave LDS, no barrier) + PV ----
    float sm = 0.f;
    f32x4 o[4];
#pragma unroll
    for (int et = 0; et < 4; ++et) o[et] = (f32x4){0.f, 0.f, 0.f, 0.f};

#pragma unroll
    for (int c = 0; c < 9; ++c) {
        float pv[8];
#pragma unroll
        for (int j = 0; j < 8; ++j) {
            const int t = 2 * c + (j >> 2);
            pv[j] = (t < 17) ? exp2f(sc[t][j & 3] - mx) : 0.f;   // log2e folded into q
            sm += pv[j];
        }
        unsigned int u0 = (unsigned)f2bf(pv[0]) | ((unsigned)f2bf(pv[1]) << 16);
        unsigned int u1 = (unsigned)f2bf(pv[2]) | ((unsigned)f2bf(pv[3]) << 16);
        unsigned int u2 = (unsigned)f2bf(pv[4]) | ((unsigned)f2bf(pv[5]) << 16);
        unsigned int u3 = (unsigned)f2bf(pv[6]) | ((unsigned)f2bf(pv[7]) << 16);
        short* pb = &Pc[wid][c & 1][0];
        *(uint2v*)(pb + fr * PCST + 4 * g)      = (uint2v){u0, u1};  // keys 4g..4g+3 (tile 2c)
        *(uint2v*)(pb + fr * PCST + 16 + 4 * g) = (uint2v){u2, u3};  // keys 16+4g..  (tile 2c+1)
        const short8 pa = *(const short8*)(pb + fr * PCST + 8 * g);  // A-frag: q=fr, k=8g..
        int ka = wid * 16 + 32 * c + 8 * g;
        ka = ka > KWIN - 8 ? KWIN - 8 : ka;        // clamped lanes have P=0
        __builtin_amdgcn_s_setprio(1);
#pragma unroll
        for (int et = 0; et < 4; ++et) {
            const short8 vb = *(const short8*)(Vs + (et * 16 + fr) * VST + ka);
            o[et] = MFMA_BF16(pa, vb, o[et], 0, 0, 0);
        }
        __builtin_amdgcn_s_setprio(0);
    }

    sm += __shfl_xor(sm, 16);
    sm += __shfl_xor(sm, 32);
    const float inv = 1.0f / sm;                   // valid for query = fr
    float inv4[4];
#pragma unroll
    for (int r = 0; r < 4; ++r) inv4[r] = __shfl(inv, 4 * g + r);   // PV D-row = query 4g+r

#pragma unroll
    for (int et = 0; et < 4; ++et)
#pragma unroll
        for (int r = 0; r < 4; ++r) {
            const int qi = q0 + wid * 16 + 4 * g + r;
            const int dd = hh * HD + et * 16 + fr;
            out[((size_t)qi * NBATCH + bb) * DMODEL + dd] = o[et][r] * inv4[r];
        }
}

extern "C" void kernel_launch(void* const* d_in, const int* in_sizes, int n_in,
                              void* d_out, int out_size, void* d_ws, size_t ws_size,
                              hipStream_t stream) {
    (void)in_sizes; (void)n_in; (void)out_size; (void)ws_size;
    const float* val = (const float*)d_in[0];
    const float* Wq  = (const float*)d_in[1];
    const float* bq  = (const float*)d_in[2];
    const float* Wk  = (const float*)d_in[3];
    const float* bk  = (const float*)d_in[4];
    const float* Wv  = (const float*)d_in[5];
    const float* bv  = (const float*)d_in[6];
    float* out = (float*)d_out;

    char* ws = (char*)d_ws;
    const size_t SZ_X  = (size_t)MROWS * DMODEL * 2;
    const size_t SZ_W  = (size_t)DMODEL * DMODEL * 2;
    short* X  = (short*)(ws);
    short* WT = (short*)(ws + SZ_X);
    short* Qb = (short*)(ws + SZ_X + 3 * SZ_W);
    short* Kb = (short*)(ws + SZ_X + 3 * SZ_W + SZ_X);
    short* Vt = (short*)(ws + SZ_X + 3 * SZ_W + 2 * SZ_X);

    cvt_val_kernel<<<dim3((MROWS * DMODEL) / 4 / 256), dim3(256), 0, stream>>>(val, X);
    cvt_w_kernel<<<dim3(3, 96, 3), dim3(256), 0, stream>>>(Wq, Wk, Wv, WT);
    gemm_qkv_kernel<<<dim3(576), dim3(512), 0, stream>>>(
        X, WT, bq, bk, bv, Qb, Kb, Vt);
    attn_kernel<<<dim3(S_LEN / QB, NBATCH * NH), dim3(512), 0, stream>>>(Qb, Kb, Vt, out);
}

// Round 8
// 92.184 us; speedup vs baseline: 1.1303x; 1.0188x over previous
//
#include <hip/hip_runtime.h>
#include <stdint.h>

typedef __attribute__((ext_vector_type(8))) short short8;
typedef __attribute__((ext_vector_type(4))) short short4v;
typedef __attribute__((ext_vector_type(4))) float f32x4;
typedef __attribute__((ext_vector_type(2))) unsigned int uint2v;

#define S_LEN 4096
#define NBATCH 2
#define DMODEL 768
#define NH 12
#define HD 64
#define MROWS (S_LEN * NBATCH)   // 8192

__device__ __forceinline__ unsigned short f2bf(float f) {
    unsigned int u = __builtin_bit_cast(unsigned int, f);
    u += 0x7fffu + ((u >> 16) & 1u);       // round-to-nearest-even
    return (unsigned short)(u >> 16);
}

// async global->LDS, 16B per lane; LDS dst = wave-uniform base + lane*16,
// global src is PER-LANE (carries the within-row slot swizzle).
#define GLDS16(gp, lp) __builtin_amdgcn_global_load_lds( \
    (const __attribute__((address_space(1))) void*)(gp), \
    (__attribute__((address_space(3))) void*)(lp), 16, 0, 0)

#define MFMA_BF16 __builtin_amdgcn_mfma_f32_16x16x32_bf16

// ---------------- kernel 1: val fp32 -> X bf16 (8192 x 768) ----------------
__global__ __launch_bounds__(256) void cvt_val_kernel(const float* __restrict__ in,
                                                      short* __restrict__ out) {
    size_t i = (size_t)blockIdx.x * 256 + threadIdx.x;
    const f32x4 v = *(const f32x4*)(in + i * 4);
    short4v o;
    o.x = (short)f2bf(v.x); o.y = (short)f2bf(v.y);
    o.z = (short)f2bf(v.z); o.w = (short)f2bf(v.w);
    *(short4v*)(out + i * 4) = o;
}

// --- kernel 2: W fp32 (K x N) -> WT bf16 (z-major, [nf][k]) ---
__global__ __launch_bounds__(256) void cvt_w_kernel(const float* __restrict__ Wq,
                                                    const float* __restrict__ Wk,
                                                    const float* __restrict__ Wv,
                                                    short* __restrict__ WT) {
    const int z = blockIdx.z;
    const float* W = (z == 0) ? Wq : ((z == 1) ? Wk : Wv);
    const int n  = blockIdx.x * 256 + threadIdx.x;
    const int k0 = blockIdx.y * 8;
    short8 o;
#pragma unroll
    for (int i = 0; i < 8; ++i)
        o[i] = (short)f2bf(W[(size_t)(k0 + i) * DMODEL + n]);
    *(short8*)(WT + (size_t)z * DMODEL * DMODEL + (size_t)n * DMODEL + k0) = o;
}

// ------- kernel 3: fused QKV GEMM, 128x256 tile, 4 waves, wave tile 64x128 -------
// acc 4x8 per wave: 12 ds_read_b128 feed 32 MFMA per K-step (0.375 reads/MFMA)
// -> LDS-read pipe balanced with MFMA pipe. 3-buffer counted-vmcnt glds
// pipeline; rule-21 slot swizzle; z==2 written transposed ([bh][e][s]).
#define NT 24   // 768/32 K-steps
__global__ __launch_bounds__(256, 2) void gemm_qkv_kernel(
    const short* __restrict__ X, const short* __restrict__ WT,
    const float* __restrict__ bq, const float* __restrict__ bk, const float* __restrict__ bv,
    short* __restrict__ Q, short* __restrict__ K, short* __restrict__ Vt)
{
    __shared__ __align__(16) short SMEM[36864];   // 72 KB: A[3][4096] | B[3][8192]; C reuse
    short* As = SMEM;            // 3 * 4096 shorts
    short* Bs = SMEM + 12288;    // 3 * 8192 shorts

    const int phys = blockIdx.x;                 // 576 = 8 XCD * (8 m * 9 n), n-fastest
    const int xcd = phys & 7, ii = phys >> 3;
    const int m0  = (xcd * 8 + ii / 9) * 128;
    const int nf  = (ii % 9) * 256;
    const int z   = nf / DMODEL;                 // exact z boundaries (256 | 768*z)
    const int n0w = nf - z * DMODEL;

    const int tid = threadIdx.x, lane = tid & 63, wid = tid >> 6;
    const int wm = wid >> 1, wn = wid & 1;       // 2M x 2N waves, wave tile 64x128
    const int fr = lane & 15, kg = lane >> 4;
    const int wr = wm * 64, wc = wn * 128;

    const float* bias = (z == 0) ? bq : ((z == 1) ? bk : bv);
    short*       OUT  = (z == 0) ? Q  : ((z == 1) ? K  : Vt);

    f32x4 acc[4][8];
#pragma unroll
    for (int i = 0; i < 4; ++i)
#pragma unroll
        for (int j = 0; j < 8; ++j) acc[i][j] = (f32x4){0.f, 0.f, 0.f, 0.f};

    // staging: lane -> row = l>>2, slot = l&3 (16B within 64B row); source slot
    // pre-swizzled gslot = (l&3)^((l>>3)&3) == (l&3)^((row>>1)&3)  (rule 21;
    // row offsets below are multiples of 8 so (row>>1)&3 is invariant).
    const int gslot = (lane & 3) ^ ((lane >> 3) & 3);
    const short* srcA = X  + (size_t)(m0 + wid * 32 + (lane >> 2)) * DMODEL + gslot * 8;
    const short* srcB = WT + (size_t)(nf + wid * 64 + (lane >> 2)) * DMODEL + gslot * 8;

#define STAGE(buf, kt) do { \
        GLDS16(srcA + (kt),               As + (buf) * 4096 + wid * 1024);        \
        GLDS16(srcA + (kt) + 16 * DMODEL, As + (buf) * 4096 + wid * 1024 + 512);  \
        GLDS16(srcB + (kt),               Bs + (buf) * 8192 + wid * 2048);        \
        GLDS16(srcB + (kt) + 16 * DMODEL, Bs + (buf) * 8192 + wid * 2048 + 512);  \
        GLDS16(srcB + (kt) + 32 * DMODEL, Bs + (buf) * 8192 + wid * 2048 + 1024); \
        GLDS16(srcB + (kt) + 48 * DMODEL, Bs + (buf) * 8192 + wid * 2048 + 1536); \
    } while (0)

    STAGE(0, 0);
    STAGE(1, 32);
    const int rslot = (fr >> 1) & 3;             // read-side swizzle (same involution)
    for (int t = 0; t < NT; ++t) {
        // per-wave wait for OWN tile-t loads (6/stage); keep t+1(,t+2) in flight
        if (t + 2 < NT) { asm volatile("s_waitcnt vmcnt(6)" ::: "memory"); }
        else            { asm volatile("s_waitcnt vmcnt(0)" ::: "memory"); }
        __builtin_amdgcn_sched_barrier(0);
        __builtin_amdgcn_s_barrier();            // tile t fully in LDS for all waves
        __builtin_amdgcn_sched_barrier(0);
        if (t + 2 < NT) STAGE((t + 2) % 3, (t + 2) * 32);   // WAR-safe post-barrier

        const short* Ab = As + (t % 3) * 4096;
        const short* Bb = Bs + (t % 3) * 8192;
        short8 af[4], bfv[8];
#pragma unroll
        for (int mi = 0; mi < 4; ++mi)
            af[mi] = *(const short8*)(Ab + (wr + mi * 16 + fr) * 32 + (kg ^ rslot) * 8);
#pragma unroll
        for (int nj = 0; nj < 8; ++nj)
            bfv[nj] = *(const short8*)(Bb + (wc + nj * 16 + fr) * 32 + (kg ^ rslot) * 8);
        __builtin_amdgcn_s_setprio(1);
#pragma unroll
        for (int mi = 0; mi < 4; ++mi)
#pragma unroll
            for (int nj = 0; nj < 8; ++nj)
                acc[mi][nj] = MFMA_BF16(af[mi], bfv[nj], acc[mi][nj], 0, 0, 0);
        __builtin_amdgcn_s_setprio(0);
    }
#undef STAGE

    __syncthreads();                        // staging LDS dead; repurpose for C tile
    // q scale folds 1/sqrt(64) AND log2(e) (attn uses exp2)
    const float scale = (z == 0) ? 0.18033688f : 1.0f;
    float bval[8];
#pragma unroll
    for (int nj = 0; nj < 8; ++nj) bval[nj] = bias[n0w + wc + nj * 16 + fr];

    if (z < 2) {                            // Q/K: [bh][s][e], coalesced short8
        short* Cs = SMEM;                   // [128][264] bf16 (33792 <= 36864)
#pragma unroll
        for (int mi = 0; mi < 4; ++mi)
#pragma unroll
            for (int nj = 0; nj < 8; ++nj)
#pragma unroll
                for (int r = 0; r < 4; ++r)
                    Cs[(wr + mi * 16 + 4 * kg + r) * 264 + (wc + nj * 16 + fr)] =
                        (short)f2bf((acc[mi][nj][r] + bval[nj]) * scale);
        __syncthreads();
#pragma unroll
        for (int it = 0; it < 16; ++it) {   // 4096 chunks of 8 elems
            const int flat = it * 256 + tid;
            const int row = flat >> 5, c8 = (flat & 31) * 8;
            const int gm = m0 + row, gn = n0w + c8;
            const int s = gm >> 1, bb = gm & 1, hh = gn >> 6, e0 = gn & 63;
            *(short8*)(&OUT[((size_t)(bb * NH + hh) * S_LEN + s) * HD + e0]) =
                *(const short8*)(&Cs[row * 264 + c8]);
        }
    } else {                                // V: write transposed [bh][e][s]
        short* Ct = SMEM;                   // [256 cols][136]: b-deinterleaved rows
#pragma unroll
        for (int mi = 0; mi < 4; ++mi)
#pragma unroll
            for (int nj = 0; nj < 8; ++nj)
#pragma unroll
                for (int r = 0; r < 4; ++r) {
                    const int row = wr + mi * 16 + 4 * kg + r;
                    const int col = wc + nj * 16 + fr;
                    Ct[col * 136 + (row & 1) * 68 + (row >> 1)] =
                        (short)f2bf(acc[mi][nj][r] + bval[nj]);
                }
        __syncthreads();
#pragma unroll
        for (int it = 0; it < 16; ++it) {   // contiguous 16B reads, coalesced stores
            const int flat = it * 256 + tid;
            const int col = flat >> 4;              // 0..255
            const int b   = (flat >> 3) & 1;
            const int sc  = flat & 7;               // 8-s chunk
            const short8 v = *(const short8*)(&Ct[col * 136 + b * 68 + sc * 8]);
            const int e = col & 63, hl = col >> 6;
            const int bh = b * NH + (n0w >> 6) + hl;
            *(short8*)(&OUT[(size_t)bh * HD * S_LEN + (size_t)e * S_LEN
                            + (m0 >> 1) + sc * 8]) = v;
        }
    }
}

// ---------------- kernel 4: banded causal attention, 8 waves x 16 queries ----------------
#define QB   128
#define KWIN 384
#define KST  72     // K LDS row stride (elems): 144B -> 4-bank rotation per row
#define VST  392    // Vt LDS row stride: 784B -> 4-bank rotation per row
#define PCST 40     // P chunk buffer row stride (80B, 16B-aligned rows)

__global__ __launch_bounds__(512, 2) void attn_kernel(
    const short* __restrict__ Q, const short* __restrict__ K,
    const short* __restrict__ Vt, float* __restrict__ out)
{
    __shared__ __align__(16) short Ks[KWIN * KST];        // 55296 B
    __shared__ __align__(16) short Vs[HD * VST];          // 50176 B
    __shared__ __align__(16) short Pc[8][2][16 * PCST];   // 20480 B  (per-wave ping-pong)

    const int tid = threadIdx.x, lane = tid & 63, wid = tid >> 6;
    const int q0 = blockIdx.x * QB;
    const int bh = blockIdx.y;
    const int bb = bh / NH, hh = bh % NH;
    const int fr = lane & 15, g = lane >> 4;
    const int kstart = q0 - 256;

    const short* Qb = Q  + (size_t)bh * S_LEN * HD;
    const short* Kb = K  + (size_t)bh * S_LEN * HD;
    const short* Vb = Vt + (size_t)bh * HD * S_LEN;

    // ---- cooperative staging (coalesced 16B segments) ----
#pragma unroll
    for (int it = 0; it < 6; ++it) {                 // K: 384 rows x 64 elems
        const int seg = it * 512 + tid;
        const int row = seg >> 3, c8 = (seg & 7) * 8;
        int sr = kstart + row; sr = sr < 0 ? 0 : sr;  // garbage rows masked later
        *(short8*)(Ks + row * KST + c8) = *(const short8*)(Kb + (size_t)sr * HD + c8);
    }
#pragma unroll
    for (int it = 0; it < 6; ++it) {                 // Vt: 64 rows x 384 key-cols
        const int seg = it * 512 + tid;
        const int row = seg / 48, cc = seg % 48;
        int sk = kstart + cc * 8; sk = sk < 0 ? 0 : sk;
        *(short8*)(Vs + row * VST + cc * 8) = *(const short8*)(Vb + (size_t)row * S_LEN + sk);
    }
    __syncthreads();

    // ---- Q fragments (B-operand: col=query=fr, k=8g+i) ----
    const int qrow = q0 + wid * 16 + fr;
    const short8 qa0 = *(const short8*)(Qb + (size_t)qrow * HD + g * 8);
    const short8 qa1 = *(const short8*)(Qb + (size_t)qrow * HD + 32 + g * 8);

    // ---- QK^T: 17 tiles ----
    float sc[17][4];
#pragma unroll
    for (int t = 0; t < 17; ++t) {
        const short* kr = Ks + ((wid + t) * 16 + fr) * KST;   // A row = key
        const short8 a0 = *(const short8*)(kr + g * 8);
        const short8 a1 = *(const short8*)(kr + 32 + g * 8);
        f32x4 d = {0.f, 0.f, 0.f, 0.f};
        __builtin_amdgcn_s_setprio(1);
        d = MFMA_BF16(a0, qa0, d, 0, 0, 0);
        d = MFMA_BF16(a1, qa1, d, 0, 0, 0);
        __builtin_amdgcn_s_setprio(0);
        const int gk0 = kstart + (wid + t) * 16 + 4 * g;      // global key (+r)
#pragma unroll
        for (int r = 0; r < 4; ++r) {
            const int dd = 256 + fr - 16 * t - 4 * g - r;     // query - key
            const bool ok = (dd >= 0) & (dd <= 256) & (gk0 + r >= 0);
            sc[t][r] = ok ? d[r] : -1e30f;
        }
    }

    // ---- softmax max (row = query = fr; reduce across g-groups) ----
    float mx = -1e30f;
#pragma unroll
    for (int t = 0; t < 17; ++t)
#pragma unroll
        for (int r = 0; r < 4; ++r) mx = fmaxf(mx, sc[t][r]);
    mx = fmaxf(mx, __shfl_xor(mx, 16));
    mx = fmaxf(mx, __shfl_xor(mx, 32));

    // ---- chunked exp2 + P redistribute (per-wave LDS, no barrier) + PV ----
    float sm = 0.f;
    f32x4 o[4];
#pragma unroll
    for (int et = 0; et < 4; ++et) o[et] = (f32x4){0.f, 0.f, 0.f, 0.f};

#pragma unroll
    for (int c = 0; c < 9; ++c) {
        float pv[8];
#pragma unroll
        for (int j = 0; j < 8; ++j) {
            const int t = 2 * c + (j >> 2);
            pv[j] = (t < 17) ? exp2f(sc[t][j & 3] - mx) : 0.f;   // log2e folded into q
            sm += pv[j];
        }
        unsigned int u0 = (unsigned)f2bf(pv[0]) | ((unsigned)f2bf(pv[1]) << 16);
        unsigned int u1 = (unsigned)f2bf(pv[2]) | ((unsigned)f2bf(pv[3]) << 16);
        unsigned int u2 = (unsigned)f2bf(pv[4]) | ((unsigned)f2bf(pv[5]) << 16);
        unsigned int u3 = (unsigned)f2bf(pv[6]) | ((unsigned)f2bf(pv[7]) << 16);
        short* pb = &Pc[wid][c & 1][0];
        *(uint2v*)(pb + fr * PCST + 4 * g)      = (uint2v){u0, u1};  // keys 4g..4g+3 (tile 2c)
        *(uint2v*)(pb + fr * PCST + 16 + 4 * g) = (uint2v){u2, u3};  // keys 16+4g..  (tile 2c+1)
        const short8 pa = *(const short8*)(pb + fr * PCST + 8 * g);  // A-frag: q=fr, k=8g..
        int ka = wid * 16 + 32 * c + 8 * g;
        ka = ka > KWIN - 8 ? KWIN - 8 : ka;        // clamped lanes have P=0
        __builtin_amdgcn_s_setprio(1);
#pragma unroll
        for (int et = 0; et < 4; ++et) {
            const short8 vb = *(const short8*)(Vs + (et * 16 + fr) * VST + ka);
            o[et] = MFMA_BF16(pa, vb, o[et], 0, 0, 0);
        }
        __builtin_amdgcn_s_setprio(0);
    }

    sm += __shfl_xor(sm, 16);
    sm += __shfl_xor(sm, 32);
    const float inv = 1.0f / sm;                   // valid for query = fr
    float inv4[4];
#pragma unroll
    for (int r = 0; r < 4; ++r) inv4[r] = __shfl(inv, 4 * g + r);   // PV D-row = query 4g+r

#pragma unroll
    for (int et = 0; et < 4; ++et)
#pragma unroll
        for (int r = 0; r < 4; ++r) {
            const int qi = q0 + wid * 16 + 4 * g + r;
            const int dd = hh * HD + et * 16 + fr;
            out[((size_t)qi * NBATCH + bb) * DMODEL + dd] = o[et][r] * inv4[r];
        }
}

extern "C" void kernel_launch(void* const* d_in, const int* in_sizes, int n_in,
                              void* d_out, int out_size, void* d_ws, size_t ws_size,
                              hipStream_t stream) {
    (void)in_sizes; (void)n_in; (void)out_size; (void)ws_size;
    const float* val = (const float*)d_in[0];
    const float* Wq  = (const float*)d_in[1];
    const float* bq  = (const float*)d_in[2];
    const float* Wk  = (const float*)d_in[3];
    const float* bk  = (const float*)d_in[4];
    const float* Wv  = (const float*)d_in[5];
    const float* bv  = (const float*)d_in[6];
    float* out = (float*)d_out;

    char* ws = (char*)d_ws;
    const size_t SZ_X  = (size_t)MROWS * DMODEL * 2;
    const size_t SZ_W  = (size_t)DMODEL * DMODEL * 2;
    short* X  = (short*)(ws);
    short* WT = (short*)(ws + SZ_X);
    short* Qb = (short*)(ws + SZ_X + 3 * SZ_W);
    short* Kb = (short*)(ws + SZ_X + 3 * SZ_W + SZ_X);
    short* Vt = (short*)(ws + SZ_X + 3 * SZ_W + 2 * SZ_X);

    cvt_val_kernel<<<dim3((MROWS * DMODEL) / 4 / 256), dim3(256), 0, stream>>>(val, X);
    cvt_w_kernel<<<dim3(3, 96, 3), dim3(256), 0, stream>>>(Wq, Wk, Wv, WT);
    gemm_qkv_kernel<<<dim3(576), dim3(256), 0, stream>>>(
        X, WT, bq, bk, bv, Qb, Kb, Vt);
    attn_kernel<<<dim3(S_LEN / QB, NBATCH * NH), dim3(512), 0, stream>>>(Qb, Kb, Vt, out);
}

// Round 9
// 84.088 us; speedup vs baseline: 1.2391x; 1.0963x over previous
//
#include <hip/hip_runtime.h>
#include <stdint.h>

typedef __attribute__((ext_vector_type(8))) short short8;
typedef __attribute__((ext_vector_type(4))) short short4v;
typedef __attribute__((ext_vector_type(4))) float f32x4;
typedef __attribute__((ext_vector_type(2))) unsigned int uint2v;

#define S_LEN 4096
#define NBATCH 2
#define DMODEL 768
#define NH 12
#define HD 64
#define MROWS (S_LEN * NBATCH)   // 8192

__device__ __forceinline__ unsigned short f2bf(float f) {
    unsigned int u = __builtin_bit_cast(unsigned int, f);
    u += 0x7fffu + ((u >> 16) & 1u);       // round-to-nearest-even
    return (unsigned short)(u >> 16);
}

// async global->LDS, 16B per lane; LDS dst = wave-uniform base + lane*16,
// global src is PER-LANE (carries the within-row slot swizzle).
#define GLDS16(gp, lp) __builtin_amdgcn_global_load_lds( \
    (const __attribute__((address_space(1))) void*)(gp), \
    (__attribute__((address_space(3))) void*)(lp), 16, 0, 0)

#define MFMA_BF16 __builtin_amdgcn_mfma_f32_16x16x32_bf16

// ---------------- kernel 1: val fp32 -> X bf16 (8192 x 768) ----------------
__global__ __launch_bounds__(256) void cvt_val_kernel(const float* __restrict__ in,
                                                      short* __restrict__ out) {
    size_t i = (size_t)blockIdx.x * 256 + threadIdx.x;
    const f32x4 v = *(const f32x4*)(in + i * 4);
    short4v o;
    o.x = (short)f2bf(v.x); o.y = (short)f2bf(v.y);
    o.z = (short)f2bf(v.z); o.w = (short)f2bf(v.w);
    *(short4v*)(out + i * 4) = o;
}

// --- kernel 2: W fp32 (K x N) -> WT bf16 (z-major, [nf][k]) ---
__global__ __launch_bounds__(256) void cvt_w_kernel(const float* __restrict__ Wq,
                                                    const float* __restrict__ Wk,
                                                    const float* __restrict__ Wv,
                                                    short* __restrict__ WT) {
    const int z = blockIdx.z;
    const float* W = (z == 0) ? Wq : ((z == 1) ? Wk : Wv);
    const int n  = blockIdx.x * 256 + threadIdx.x;
    const int k0 = blockIdx.y * 8;
    short8 o;
#pragma unroll
    for (int i = 0; i < 8; ++i)
        o[i] = (short)f2bf(W[(size_t)(k0 + i) * DMODEL + n]);
    *(short8*)(WT + (size_t)z * DMODEL * DMODEL + (size_t)n * DMODEL + k0) = o;
}

// ------- kernel 3: fused QKV GEMM, 128x192 tile, 4 waves, wave tile 64x96 -------
// acc 4x6 (~160 VGPR -> 3 waves/SIMD); 2-buffer 2-barrier counted-vmcnt
// pipeline; 10 ds_read feed 24 MFMA per wave-step (LDS bytes/FLOP -20% vs
// 64x64); 3 blocks/CU = 12 waves/CU. MFMA cluster placed between stage-issue
// and vmcnt gate to hide glds latency. z==2 written transposed ([bh][e][s]).
#define NT 24   // 768/32 K-steps
__global__ __launch_bounds__(256, 3) void gemm_qkv_kernel(
    const short* __restrict__ X, const short* __restrict__ WT,
    const float* __restrict__ bq, const float* __restrict__ bk, const float* __restrict__ bv,
    short* __restrict__ Q, short* __restrict__ K, short* __restrict__ Vt)
{
    __shared__ __align__(16) short SMEM[26112];  // 51KB: stage A[2][4096]|B[2][6144]; C reuse
    short* As = SMEM;            // 2 * 4096 shorts
    short* Bs = SMEM + 8192;     // 2 * 6144 shorts

    const int phys = blockIdx.x;                 // 768 = 8 XCD * (8 m * 12 n), n-fastest
    const int xcd = phys & 7, ii = phys >> 3;
    const int m0  = (xcd * 8 + ii / 12) * 128;
    const int nf  = (ii % 12) * 192;
    const int z   = nf / DMODEL;                 // 4 n-tiles per z (exact boundaries)
    const int n0w = nf - z * DMODEL;

    const int tid = threadIdx.x, lane = tid & 63, wid = tid >> 6;
    const int wm = wid >> 1, wn = wid & 1;       // 2M x 2N waves, wave tile 64x96
    const int fr = lane & 15, kg = lane >> 4;
    const int wr = wm * 64, wc = wn * 96;

    const float* bias = (z == 0) ? bq : ((z == 1) ? bk : bv);
    short*       OUT  = (z == 0) ? Q  : ((z == 1) ? K  : Vt);

    f32x4 acc[4][6];
#pragma unroll
    for (int i = 0; i < 4; ++i)
#pragma unroll
        for (int j = 0; j < 6; ++j) acc[i][j] = (f32x4){0.f, 0.f, 0.f, 0.f};

    // staging: lane -> row = l>>2, slot = l&3; source slot pre-swizzled
    // gslot = (l&3)^((l>>3)&3) (rule 21; row offsets below are multiples of 16).
    const int gslot = (lane & 3) ^ ((lane >> 3) & 3);
    const short* srcA = X  + (size_t)(m0 + wid * 32 + (lane >> 2)) * DMODEL + gslot * 8;
    const short* srcB = WT + (size_t)(nf + wid * 48 + (lane >> 2)) * DMODEL + gslot * 8;

#define STAGE(buf, kt) do { \
        GLDS16(srcA + (kt),               As + (buf) * 4096 + wid * 1024);        \
        GLDS16(srcA + (kt) + 16 * DMODEL, As + (buf) * 4096 + wid * 1024 + 512);  \
        GLDS16(srcB + (kt),               Bs + (buf) * 6144 + wid * 1536);        \
        GLDS16(srcB + (kt) + 16 * DMODEL, Bs + (buf) * 6144 + wid * 1536 + 512);  \
        GLDS16(srcB + (kt) + 32 * DMODEL, Bs + (buf) * 6144 + wid * 1536 + 1024); \
    } while (0)

    // prologue: tiles 0,1 in flight; wait tile 0 only (tile 1 crosses barrier)
    STAGE(0, 0);
    STAGE(1, 32);
    asm volatile("s_waitcnt vmcnt(5)" ::: "memory");
    __builtin_amdgcn_sched_barrier(0);
    __builtin_amdgcn_s_barrier();

    const int rslot = (fr >> 1) & 3;             // read-side swizzle (same involution)
    for (int t = 0; t < NT; ++t) {
        const short* Ab = As + (t & 1) * 4096;
        const short* Bb = Bs + (t & 1) * 6144;
        short8 af[4], bfv[6];
#pragma unroll
        for (int mi = 0; mi < 4; ++mi)
            af[mi] = *(const short8*)(Ab + (wr + mi * 16 + fr) * 32 + (kg ^ rslot) * 8);
#pragma unroll
        for (int nj = 0; nj < 6; ++nj)
            bfv[nj] = *(const short8*)(Bb + (wc + nj * 16 + fr) * 32 + (kg ^ rslot) * 8);
        asm volatile("s_waitcnt lgkmcnt(0)" ::: "memory");   // my reads done
        __builtin_amdgcn_sched_barrier(0);
        __builtin_amdgcn_s_barrier();            // B1: ALL waves' reads of buf[t&1] done
        __builtin_amdgcn_sched_barrier(0);
        if (t + 2 < NT) STAGE(t & 1, (t + 2) * 32);          // WAR-safe overwrite
        __builtin_amdgcn_sched_barrier(0);

        __builtin_amdgcn_s_setprio(1);           // MFMA hides glds issue + latency
#pragma unroll
        for (int mi = 0; mi < 4; ++mi)
#pragma unroll
            for (int nj = 0; nj < 6; ++nj)
                acc[mi][nj] = MFMA_BF16(af[mi], bfv[nj], acc[mi][nj], 0, 0, 0);
        __builtin_amdgcn_s_setprio(0);

        // gate: my tile-(t+1) loads landed (t+2 stays in flight); then sync
        if (t + 2 < NT) { asm volatile("s_waitcnt vmcnt(5)" ::: "memory"); }
        else            { asm volatile("s_waitcnt vmcnt(0)" ::: "memory"); }
        __builtin_amdgcn_sched_barrier(0);
        __builtin_amdgcn_s_barrier();            // B2: tile t+1 visible to all waves
    }
#undef STAGE

    // ---- epilogue (staging reads all retired at B1 of t=23) ----
    const float scale = (z == 0) ? 0.18033688f : 1.0f;  // q: 1/sqrt(64) * log2(e)
    float bval[6];
#pragma unroll
    for (int nj = 0; nj < 6; ++nj) bval[nj] = bias[n0w + wc + nj * 16 + fr];

    if (z < 2) {                            // Q/K: [bh][s][e], coalesced short8
        short* Cs = SMEM;                   // [128][200] bf16 (25600 <= 26112)
#pragma unroll
        for (int mi = 0; mi < 4; ++mi)
#pragma unroll
            for (int nj = 0; nj < 6; ++nj)
#pragma unroll
                for (int r = 0; r < 4; ++r)
                    Cs[(wr + mi * 16 + 4 * kg + r) * 200 + (wc + nj * 16 + fr)] =
                        (short)f2bf((acc[mi][nj][r] + bval[nj]) * scale);
        __syncthreads();
#pragma unroll
        for (int it = 0; it < 12; ++it) {   // 3072 chunks of 8 elems
            const int flat = it * 256 + tid;
            const int row = flat / 24, c8 = (flat % 24) * 8;
            const int gm = m0 + row, gn = n0w + c8;
            const int s = gm >> 1, bb = gm & 1, hh = gn >> 6, e0 = gn & 63;
            *(short8*)(&OUT[((size_t)(bb * NH + hh) * S_LEN + s) * HD + e0]) =
                *(const short8*)(&Cs[row * 200 + c8]);
        }
    } else {                                // V: write transposed [bh][e][s]
        short* Ct = SMEM;                   // [192 cols][136]: b-deinterleaved rows
#pragma unroll
        for (int mi = 0; mi < 4; ++mi)
#pragma unroll
            for (int nj = 0; nj < 6; ++nj)
#pragma unroll
                for (int r = 0; r < 4; ++r) {
                    const int row = wr + mi * 16 + 4 * kg + r;
                    const int col = wc + nj * 16 + fr;
                    Ct[col * 136 + (row & 1) * 68 + (row >> 1)] =
                        (short)f2bf(acc[mi][nj][r] + bval[nj]);
                }
        __syncthreads();
#pragma unroll
        for (int it = 0; it < 12; ++it) {   // 8B-aligned LDS reads, coalesced stores
            const int flat = it * 256 + tid;
            const int col = flat >> 4;              // 0..191
            const int b   = (flat >> 3) & 1;
            const int sc  = flat & 7;               // 8-s chunk
            const short* base = &Ct[col * 136 + b * 68 + sc * 8];
            short8 v;
            *(short4v*)&v      = *(const short4v*)(base);
            *((short4v*)&v + 1) = *(const short4v*)(base + 4);
            const int e = col & 63, hl = col >> 6;
            const int bh = b * NH + (n0w >> 6) + hl;
            *(short8*)(&OUT[(size_t)bh * HD * S_LEN + (size_t)e * S_LEN
                            + (m0 >> 1) + sc * 8]) = v;
        }
    }
}

// ---------------- kernel 4: banded causal attention, 8 waves x 16 queries ----------------
#define QB   128
#define KWIN 384
#define KST  72     // K LDS row stride (elems): 144B -> 4-bank rotation per row
#define VST  392    // Vt LDS row stride: 784B -> 4-bank rotation per row
#define PCST 40     // P chunk buffer row stride (80B, 16B-aligned rows)

__global__ __launch_bounds__(512, 2) void attn_kernel(
    const short* __restrict__ Q, const short* __restrict__ K,
    const short* __restrict__ Vt, float* __restrict__ out)
{
    __shared__ __align__(16) short Ks[KWIN * KST];        // 55296 B
    __shared__ __align__(16) short Vs[HD * VST];          // 50176 B
    __shared__ __align__(16) short Pc[8][2][16 * PCST];   // 20480 B  (per-wave ping-pong)

    const int tid = threadIdx.x, lane = tid & 63, wid = tid >> 6;
    const int q0 = blockIdx.x * QB;
    const int bh = blockIdx.y;
    const int bb = bh / NH, hh = bh % NH;
    const int fr = lane & 15, g = lane >> 4;
    const int kstart = q0 - 256;

    const short* Qb = Q  + (size_t)bh * S_LEN * HD;
    const short* Kb = K  + (size_t)bh * S_LEN * HD;
    const short* Vb = Vt + (size_t)bh * HD * S_LEN;

    // ---- cooperative staging (coalesced 16B segments) ----
#pragma unroll
    for (int it = 0; it < 6; ++it) {                 // K: 384 rows x 64 elems
        const int seg = it * 512 + tid;
        const int row = seg >> 3, c8 = (seg & 7) * 8;
        int sr = kstart + row; sr = sr < 0 ? 0 : sr;  // garbage rows masked later
        *(short8*)(Ks + row * KST + c8) = *(const short8*)(Kb + (size_t)sr * HD + c8);
    }
#pragma unroll
    for (int it = 0; it < 6; ++it) {                 // Vt: 64 rows x 384 key-cols
        const int seg = it * 512 + tid;
        const int row = seg / 48, cc = seg % 48;
        int sk = kstart + cc * 8; sk = sk < 0 ? 0 : sk;
        *(short8*)(Vs + row * VST + cc * 8) = *(const short8*)(Vb + (size_t)row * S_LEN + sk);
    }
    __syncthreads();

    // ---- Q fragments (B-operand: col=query=fr, k=8g+i) ----
    const int qrow = q0 + wid * 16 + fr;
    const short8 qa0 = *(const short8*)(Qb + (size_t)qrow * HD + g * 8);
    const short8 qa1 = *(const short8*)(Qb + (size_t)qrow * HD + 32 + g * 8);

    // ---- QK^T: 17 tiles ----
    float sc[17][4];
#pragma unroll
    for (int t = 0; t < 17; ++t) {
        const short* kr = Ks + ((wid + t) * 16 + fr) * KST;   // A row = key
        const short8 a0 = *(const short8*)(kr + g * 8);
        const short8 a1 = *(const short8*)(kr + 32 + g * 8);
        f32x4 d = {0.f, 0.f, 0.f, 0.f};
        __builtin_amdgcn_s_setprio(1);
        d = MFMA_BF16(a0, qa0, d, 0, 0, 0);
        d = MFMA_BF16(a1, qa1, d, 0, 0, 0);
        __builtin_amdgcn_s_setprio(0);
        const int gk0 = kstart + (wid + t) * 16 + 4 * g;      // global key (+r)
#pragma unroll
        for (int r = 0; r < 4; ++r) {
            const int dd = 256 + fr - 16 * t - 4 * g - r;     // query - key
            const bool ok = (dd >= 0) & (dd <= 256) & (gk0 + r >= 0);
            sc[t][r] = ok ? d[r] : -1e30f;
        }
    }

    // ---- softmax max (row = query = fr; reduce across g-groups) ----
    float mx = -1e30f;
#pragma unroll
    for (int t = 0; t < 17; ++t)
#pragma unroll
        for (int r = 0; r < 4; ++r) mx = fmaxf(mx, sc[t][r]);
    mx = fmaxf(mx, __shfl_xor(mx, 16));
    mx = fmaxf(mx, __shfl_xor(mx, 32));

    // ---- chunked exp2 + P redistribute (per-wave LDS, no barrier) + PV ----
    float sm = 0.f;
    f32x4 o[4];
#pragma unroll
    for (int et = 0; et < 4; ++et) o[et] = (f32x4){0.f, 0.f, 0.f, 0.f};

#pragma unroll
    for (int c = 0; c < 9; ++c) {
        float pv[8];
#pragma unroll
        for (int j = 0; j < 8; ++j) {
            const int t = 2 * c + (j >> 2);
            pv[j] = (t < 17) ? exp2f(sc[t][j & 3] - mx) : 0.f;   // log2e folded into q
            sm += pv[j];
        }
        unsigned int u0 = (unsigned)f2bf(pv[0]) | ((unsigned)f2bf(pv[1]) << 16);
        unsigned int u1 = (unsigned)f2bf(pv[2]) | ((unsigned)f2bf(pv[3]) << 16);
        unsigned int u2 = (unsigned)f2bf(pv[4]) | ((unsigned)f2bf(pv[5]) << 16);
        unsigned int u3 = (unsigned)f2bf(pv[6]) | ((unsigned)f2bf(pv[7]) << 16);
        short* pb = &Pc[wid][c & 1][0];
        *(uint2v*)(pb + fr * PCST + 4 * g)      = (uint2v){u0, u1};  // keys 4g..4g+3 (tile 2c)
        *(uint2v*)(pb + fr * PCST + 16 + 4 * g) = (uint2v){u2, u3};  // keys 16+4g..  (tile 2c+1)
        const short8 pa = *(const short8*)(pb + fr * PCST + 8 * g);  // A-frag: q=fr, k=8g..
        int ka = wid * 16 + 32 * c + 8 * g;
        ka = ka > KWIN - 8 ? KWIN - 8 : ka;        // clamped lanes have P=0
        __builtin_amdgcn_s_setprio(1);
#pragma unroll
        for (int et = 0; et < 4; ++et) {
            const short8 vb = *(const short8*)(Vs + (et * 16 + fr) * VST + ka);
            o[et] = MFMA_BF16(pa, vb, o[et], 0, 0, 0);
        }
        __builtin_amdgcn_s_setprio(0);
    }

    sm += __shfl_xor(sm, 16);
    sm += __shfl_xor(sm, 32);
    const float inv = 1.0f / sm;                   // valid for query = fr
    float inv4[4];
#pragma unroll
    for (int r = 0; r < 4; ++r) inv4[r] = __shfl(inv, 4 * g + r);   // PV D-row = query 4g+r

#pragma unroll
    for (int et = 0; et < 4; ++et)
#pragma unroll
        for (int r = 0; r < 4; ++r) {
            const int qi = q0 + wid * 16 + 4 * g + r;
            const int dd = hh * HD + et * 16 + fr;
            out[((size_t)qi * NBATCH + bb) * DMODEL + dd] = o[et][r] * inv4[r];
        }
}

extern "C" void kernel_launch(void* const* d_in, const int* in_sizes, int n_in,
                              void* d_out, int out_size, void* d_ws, size_t ws_size,
                              hipStream_t stream) {
    (void)in_sizes; (void)n_in; (void)out_size; (void)ws_size;
    const float* val = (const float*)d_in[0];
    const float* Wq  = (const float*)d_in[1];
    const float* bq  = (const float*)d_in[2];
    const float* Wk  = (const float*)d_in[3];
    const float* bk  = (const float*)d_in[4];
    const float* Wv  = (const float*)d_in[5];
    const float* bv  = (const float*)d_in[6];
    float* out = (float*)d_out;

    char* ws = (char*)d_ws;
    const size_t SZ_X  = (size_t)MROWS * DMODEL * 2;
    const size_t SZ_W  = (size_t)DMODEL * DMODEL * 2;
    short* X  = (short*)(ws);
    short* WT = (short*)(ws + SZ_X);
    short* Qb = (short*)(ws + SZ_X + 3 * SZ_W);
    short* Kb = (short*)(ws + SZ_X + 3 * SZ_W + SZ_X);
    short* Vt = (short*)(ws + SZ_X + 3 * SZ_W + 2 * SZ_X);

    cvt_val_kernel<<<dim3((MROWS * DMODEL) / 4 / 256), dim3(256), 0, stream>>>(val, X);
    cvt_w_kernel<<<dim3(3, 96, 3), dim3(256), 0, stream>>>(Wq, Wk, Wv, WT);
    gemm_qkv_kernel<<<dim3(768), dim3(256), 0, stream>>>(
        X, WT, bq, bk, bv, Qb, Kb, Vt);
    attn_kernel<<<dim3(S_LEN / QB, NBATCH * NH), dim3(512), 0, stream>>>(Qb, Kb, Vt, out);
}